// Round 3
// baseline (1253.556 us; speedup 1.0000x reference)
//
#include <hip/hip_runtime.h>
#include <hip/hip_bf16.h>

#define DEV __device__ __forceinline__

constexpr int Bc = 2, Nc = 2048, Mc = 2048, DIMc = 512, Hc = 8, FFc = 2048, Ec = 64;
constexpr int CT = 64;            // causal chunk length (tokens)
constexpr int NCc = Nc / CT;      // 32 chunks per sequence
constexpr float LN_EPS = 1e-5f, ATTN_EPS = 1e-6f;

// ---------------- dtype detection + ingest to canonical fp32 ----------------
// bf16 data misread as fp32 looks plausible; fp32 data misread as bf16 does not.
// So: interpret first 512 elements of x as bf16; if ANY is NaN/|v|>1e4 -> fp32.
__global__ __launch_bounds__(64) void detect_kernel(const void* x, int* flag) {
  const unsigned short* u = (const unsigned short*)x;
  int tid = threadIdx.x;
  int bad = 0;
#pragma unroll
  for (int i = 0; i < 8; ++i) {
    float v = __uint_as_float(((unsigned)u[tid * 8 + i]) << 16);
    if (!(fabsf(v) <= 1e4f)) bad = 1;   // catches NaN, Inf, garbage
  }
  unsigned long long m = __ballot(bad);
  if (tid == 0) *flag = (m == 0ull) ? 1 : 0;  // 1 = inputs are bf16
}

struct ConvJob { const void* src; float* dst; int n; };
struct ConvJobs { ConvJob j[18]; };

__global__ __launch_bounds__(256) void ingest_kernel(ConvJobs jobs, const int* flag) {
  int bf = *flag;
  ConvJob jb = jobs.j[blockIdx.y];
  int stride = gridDim.x * 256;
  for (int i = blockIdx.x * 256 + threadIdx.x; i < jb.n; i += stride) {
    float v;
    if (bf) v = __uint_as_float(((unsigned)((const unsigned short*)jb.src)[i]) << 16);
    else    v = ((const float*)jb.src)[i];
    jb.dst[i] = v;
  }
}

// ---------------- generic tiled GEMM: C[M,N] = A[M,K] @ W[K,N] + bias (+res)(relu) ---
// block 256 (16x16), 64x64 tile, 4x4 per thread, K-tile 16. All fp32.
template<bool RELU, bool ADD_RES>
__global__ __launch_bounds__(256) void gemm_kernel(
    const float* __restrict__ A, const float* __restrict__ W,
    const float* __restrict__ bias, const float* __restrict__ res,
    float* __restrict__ C, int M, int N, int K)
{
  __shared__ float As[16][65];
  __shared__ float Bs[16][65];
  int tid = threadIdx.x;
  int tx = tid & 15, ty = tid >> 4;
  int row0 = blockIdx.y * 64, col0 = blockIdx.x * 64;
  float acc[4][4] = {};
  for (int k0 = 0; k0 < K; k0 += 16) {
#pragma unroll
    for (int j = 0; j < 4; ++j) {      // A tile: 64 rows x 16 k
      int i = tid + 256 * j;
      int m = i >> 4, kk = i & 15;
      As[kk][m] = A[(size_t)(row0 + m) * K + k0 + kk];
    }
#pragma unroll
    for (int j = 0; j < 4; ++j) {      // W tile: 16 k x 64 cols
      int i = tid + 256 * j;
      int kk = i >> 6, n = i & 63;
      Bs[kk][n] = W[(size_t)(k0 + kk) * N + col0 + n];
    }
    __syncthreads();
#pragma unroll
    for (int kk = 0; kk < 16; ++kk) {
      float a[4], b[4];
#pragma unroll
      for (int u = 0; u < 4; ++u) a[u] = As[kk][ty * 4 + u];
#pragma unroll
      for (int u = 0; u < 4; ++u) b[u] = Bs[kk][tx * 4 + u];
#pragma unroll
      for (int u = 0; u < 4; ++u)
#pragma unroll
        for (int w = 0; w < 4; ++w) acc[u][w] += a[u] * b[w];
    }
    __syncthreads();
  }
#pragma unroll
  for (int u = 0; u < 4; ++u) {
    int m = row0 + ty * 4 + u;
#pragma unroll
    for (int w = 0; w < 4; ++w) {
      int n = col0 + tx * 4 + w;
      float v = acc[u][w] + bias[n];
      if (ADD_RES) v += res[(size_t)m * N + n];
      if (RELU) v = fmaxf(v, 0.f);
      C[(size_t)m * N + n] = v;
    }
  }
}

// ---------------- layernorm over last dim (512), optional residual ----------------
// FINAL: writes d_out as bf16 if *flag==1 else fp32. Safe with out aliasing in/res.
template<bool HAS_RES, bool FINAL>
__global__ __launch_bounds__(256) void ln_kernel(
    const float* __restrict__ in, const float* __restrict__ res,
    const float* __restrict__ g, const float* __restrict__ b,
    void* __restrict__ out, const int* __restrict__ flag)
{
  int row = blockIdx.x, tid = threadIdx.x;
  size_t base = (size_t)row * DIMc;
  float x0 = in[base + tid], x1 = in[base + tid + 256];
  if (HAS_RES) { x0 += res[base + tid]; x1 += res[base + tid + 256]; }
  float s1 = x0 + x1, s2 = x0 * x0 + x1 * x1;
#pragma unroll
  for (int off = 1; off < 64; off <<= 1) { s1 += __shfl_xor(s1, off); s2 += __shfl_xor(s2, off); }
  __shared__ float p1[4], p2[4], stat[2];
  if ((tid & 63) == 0) { p1[tid >> 6] = s1; p2[tid >> 6] = s2; }
  __syncthreads();
  if (tid == 0) {
    float t1 = p1[0] + p1[1] + p1[2] + p1[3];
    float t2 = p2[0] + p2[1] + p2[2] + p2[3];
    float mu = t1 / DIMc;
    float var = t2 / DIMc - mu * mu;
    stat[0] = mu; stat[1] = rsqrtf(var + LN_EPS);
  }
  __syncthreads();
  float mu = stat[0], rv = stat[1];
  float y0 = (x0 - mu) * rv * g[tid] + b[tid];
  float y1 = (x1 - mu) * rv * g[tid + 256] + b[tid + 256];
  if (FINAL) {
    if (*flag) {
      __hip_bfloat16* o = (__hip_bfloat16*)out;
      o[base + tid] = __float2bfloat16(y0);
      o[base + tid + 256] = __float2bfloat16(y1);
    } else {
      float* o = (float*)out;
      o[base + tid] = y0;
      o[base + tid + 256] = y1;
    }
  } else {
    float* o = (float*)out;
    o[base + tid] = y0;
    o[base + tid + 256] = y1;
  }
}

// ---------------- causal linear attention, pass A: per-chunk KV sums ----------------
// qvk layout: [b][n][3*DIM], q at 0, v at DIM, k at 2*DIM (reference split order q,v,k)
__global__ __launch_bounds__(256) void causalA(const float* __restrict__ qvk,
    float* __restrict__ chunkKV, float* __restrict__ chunkKs)
{
  int c = blockIdx.x, bh = blockIdx.y;
  int b = bh >> 3, h = bh & 7;
  __shared__ float ks[CT][Ec];
  __shared__ float vs[CT][Ec];
  int tid = threadIdx.x;
#pragma unroll
  for (int j = 0; j < 16; ++j) {
    int i = tid + 256 * j;
    int t = i >> 6, d = i & 63;
    size_t rowbase = ((size_t)b * Nc + c * CT + t) * (3 * DIMc);
    ks[t][d] = __expf(qvk[rowbase + 2 * DIMc + h * Ec + d]);
    vs[t][d] = qvk[rowbase + DIMc + h * Ec + d];
  }
  __syncthreads();
  int e = tid & 63, d0 = tid >> 6;
  float acc[16] = {};
  for (int t = 0; t < CT; ++t) {
    float ve = vs[t][e];
#pragma unroll
    for (int j = 0; j < 16; ++j) acc[j] += ks[t][d0 + 4 * j] * ve;
  }
  size_t obase = ((size_t)bh * NCc + c) * (Ec * Ec);
#pragma unroll
  for (int j = 0; j < 16; ++j) chunkKV[obase + (size_t)(d0 + 4 * j) * Ec + e] = acc[j];
  if (tid < Ec) {
    float s = 0;
    for (int t = 0; t < CT; ++t) s += ks[t][tid];
    chunkKs[((size_t)bh * NCc + c) * Ec + tid] = s;
  }
}

// ---------------- pass B: in-place exclusive prefix over chunks ----------------
__global__ __launch_bounds__(256) void causalB(float* __restrict__ chunkKV,
                                               float* __restrict__ chunkKs)
{
  int bh = blockIdx.x, tid = threadIdx.x;
  for (int idx = tid; idx < Ec * Ec; idx += 256) {
    float run = 0;
    size_t base = (size_t)bh * NCc * Ec * Ec + idx;
    for (int c = 0; c < NCc; ++c) {
      float t = chunkKV[base + (size_t)c * Ec * Ec];
      chunkKV[base + (size_t)c * Ec * Ec] = run;
      run += t;
    }
  }
  if (tid < Ec) {
    float run = 0;
    size_t base = (size_t)bh * NCc * Ec + tid;
    for (int c = 0; c < NCc; ++c) {
      float t = chunkKs[base + (size_t)c * Ec];
      chunkKs[base + (size_t)c * Ec] = run;
      run += t;
    }
  }
}

// ---------------- pass C: per-token outputs ----------------
__global__ __launch_bounds__(256) void causalC(const float* __restrict__ qvk,
    const float* __restrict__ chunkKV, const float* __restrict__ chunkKs,
    float* __restrict__ attn_out)
{
  int c = blockIdx.x, bh = blockIdx.y;
  int b = bh >> 3, h = bh & 7;
  __shared__ float S[Ec][Ec];        // exclusive KV prefix
  __shared__ float ks[CT][Ec + 1];
  __shared__ float vs[CT][Ec];
  __shared__ float kpre[Ec];
  int tid = threadIdx.x;
  size_t kvb = (size_t)bh * NCc + c;
#pragma unroll
  for (int j = 0; j < 16; ++j) {
    int i = tid + 256 * j;
    int t = i >> 6, d = i & 63;
    S[t][d] = chunkKV[kvb * (Ec * Ec) + i];
    size_t rowbase = ((size_t)b * Nc + c * CT + t) * (3 * DIMc);
    ks[t][d] = __expf(qvk[rowbase + 2 * DIMc + h * Ec + d]);
    vs[t][d] = qvk[rowbase + DIMc + h * Ec + d];
  }
  if (tid < Ec) kpre[tid] = chunkKs[kvb * Ec + tid] + ATTN_EPS;
  __syncthreads();
  int w = tid >> 6, lane = tid & 63;
  for (int ti = 0; ti < 16; ++ti) {
    int t = w * 16 + ti;  // token index within chunk (uniform per wave)
    size_t rowbase = ((size_t)b * Nc + c * CT + t) * (3 * DIMc);
    float qv = qvk[rowbase + h * Ec + lane];
    float mx = qv;
#pragma unroll
    for (int off = 1; off < 64; off <<= 1) mx = fmaxf(mx, __shfl_xor(mx, off));
    float ex = __expf(qv - mx);
    float ssum = ex;
#pragma unroll
    for (int off = 1; off < 64; off <<= 1) ssum += __shfl_xor(ssum, off);
    float qs = ex / ssum * 0.125f;     // softmax(q)[lane] * E^-0.5
    // intra-chunk score for tau = lane
    float a = 0;
    for (int d = 0; d < Ec; ++d) a += __shfl(qs, d) * ks[lane][d];
    float am = (lane <= t) ? a : 0.f;
    // denominator
    float r = am + qs * kpre[lane];
#pragma unroll
    for (int off = 1; off < 64; off <<= 1) r += __shfl_xor(r, off);
    float dinv = 1.f / r;
    // output element e = lane
    float acc = 0;
    for (int d = 0; d < Ec; ++d) acc += __shfl(qs, d) * S[d][lane];
    for (int tau = 0; tau <= t; ++tau) acc += __shfl(am, tau) * vs[tau][lane];
    attn_out[((size_t)b * Nc + c * CT + t) * DIMc + h * Ec + lane] = acc * dinv;
  }
}

// ---------------- cross-attn: column softmax sums of exp(k2) over m ----------------
__global__ __launch_bounds__(256) void colsum_kernel(const float* __restrict__ kvbuf,
                                                     float* __restrict__ colsum)
{
  int bh = blockIdx.x;
  int b = bh >> 3, h = bh & 7;
  int tid = threadIdx.x, w = tid >> 6, lane = tid & 63;
  float s = 0;
  for (int m = w; m < Mc; m += 4)
    s += __expf(kvbuf[((size_t)b * Mc + m) * (2 * DIMc) + h * Ec + lane]);
  __shared__ float p[4][Ec];
  p[w][lane] = s;
  __syncthreads();
  if (tid < Ec) colsum[(size_t)bh * Ec + tid] = p[0][tid] + p[1][tid] + p[2][tid] + p[3][tid];
}

// ---------------- cross-attn: ctx[d,e] = sum_m softmax_col(k2)[m,d] * v2[m,e] --------
__global__ __launch_bounds__(256) void ctx_kernel(const float* __restrict__ kvbuf,
    const float* __restrict__ colsum, float* __restrict__ ctx)
{
  int slab = blockIdx.x, bh = blockIdx.y;
  int b = bh >> 3, h = bh & 7;
  __shared__ float ks[64][Ec];
  __shared__ float vs[64][Ec];
  int tid = threadIdx.x;
#pragma unroll
  for (int j = 0; j < 16; ++j) {
    int i = tid + 256 * j;
    int m = i >> 6, d = i & 63;
    size_t rowbase = ((size_t)b * Mc + slab * 64 + m) * (2 * DIMc);
    ks[m][d] = __expf(kvbuf[rowbase + h * Ec + d]) / colsum[(size_t)bh * Ec + d];
    vs[m][d] = kvbuf[rowbase + DIMc + h * Ec + d];
  }
  __syncthreads();
  int e = tid & 63, d0 = tid >> 6;
  float acc[16] = {};
  for (int m = 0; m < 64; ++m) {
    float ve = vs[m][e];
#pragma unroll
    for (int j = 0; j < 16; ++j) acc[j] += ks[m][d0 + 4 * j] * ve;
  }
  size_t obase = (size_t)bh * Ec * Ec;
#pragma unroll
  for (int j = 0; j < 16; ++j) atomicAdd(&ctx[obase + (size_t)(d0 + 4 * j) * Ec + e], acc[j]);
}

// ---------------- cross-attn: out[t,e] = softmax(q2[t])*E^-.5 @ ctx ----------------
__global__ __launch_bounds__(256) void attn2_kernel(const float* __restrict__ q2,
    const float* __restrict__ ctx, float* __restrict__ out)
{
  int bh = blockIdx.y;
  int b = bh >> 3, h = bh & 7;
  __shared__ float cs[Ec][Ec];
  int tid = threadIdx.x;
#pragma unroll
  for (int j = 0; j < 16; ++j) {
    int i = tid + 256 * j;
    cs[i >> 6][i & 63] = ctx[(size_t)bh * Ec * Ec + i];
  }
  __syncthreads();
  int w = tid >> 6, lane = tid & 63;
  int t = blockIdx.x * 4 + w;
  float qv = q2[((size_t)b * Nc + t) * DIMc + h * Ec + lane];
  float mx = qv;
#pragma unroll
  for (int off = 1; off < 64; off <<= 1) mx = fmaxf(mx, __shfl_xor(mx, off));
  float ex = __expf(qv - mx);
  float ssum = ex;
#pragma unroll
  for (int off = 1; off < 64; off <<= 1) ssum += __shfl_xor(ssum, off);
  float qs = ex / ssum * 0.125f;
  float acc = 0;
  for (int d = 0; d < Ec; ++d) acc += __shfl(qs, d) * cs[d][lane];
  out[((size_t)b * Nc + t) * DIMc + h * Ec + lane] = acc;
}

extern "C" void kernel_launch(void* const* d_in, const int* in_sizes, int n_in,
                              void* d_out, int out_size, void* d_ws, size_t ws_size,
                              hipStream_t stream)
{
  // ---- workspace layout (fp32 elements) ----
  // [0,64): flag (int in first 4 bytes)
  // conv region: fp32 copies of all 18 inputs (7,873,024 floats)
  // pipeline region (14.78M floats), aliased:
  //   region0 [0, 8.39M): qvk (6.29M) -> kvbuf (4.19M)+q2 (2.10M) -> ff1buf (8.39M)
  //   out1, attn_o (-> attn2_o -> ybuf in-place), r3 (chunkKV -> pre3), smalls
  float* ws = (float*)d_ws;
  int* flag = (int*)ws;
  float* conv = ws + 64;

  // fp32 copies of inputs, in dict order
  float* cin[18];
  size_t off = 0;
  for (int i = 0; i < 18; ++i) { cin[i] = conv + off; off += (size_t)in_sizes[i]; }
  float* pipe = conv + off;

  const size_t SZ_ROW  = (size_t)Bc * Nc * DIMc;       // 2,097,152
  const size_t SZ_KV   = (size_t)Bc * Mc * 2 * DIMc;   // 4,194,304
  const size_t SZ_FF1  = (size_t)Bc * Nc * FFc;        // 8,388,608
  float* region0 = pipe;
  float* qvk     = region0;            // live: gemm1 .. causalC
  float* kvbuf   = region0;            // live: kvGEMM .. ctx_kernel
  float* q2      = region0 + SZ_KV;    // live: q2GEMM .. attn2
  float* ff1buf  = region0;            // live: ff1 .. ff2
  float* out1    = pipe + SZ_FF1;                   // live: LN1 .. LN2
  float* attn_o  = pipe + SZ_FF1 + SZ_ROW;          // attn_o -> attn2_o -> ybuf
  float* r3      = pipe + SZ_FF1 + 2 * SZ_ROW;      // chunkKV -> pre3
  float* chunkKV = r3;
  float* pre3    = r3;
  float* chunkKs = pipe + SZ_FF1 + 3 * SZ_ROW;                    // 32768
  float* colsum  = chunkKs + (size_t)Bc * Hc * NCc * Ec;          // 1024
  float* ctx2    = colsum + (size_t)Bc * Hc * Ec;                 // 65536
  float* ybuf    = attn_o;
  float* attn2_o = attn_o;
  (void)ws_size; (void)n_in; (void)out_size;

  dim3 blk(256);
  const int MR = Bc * Nc;  // 4096 rows

  // 0. detect input dtype, convert everything to fp32
  detect_kernel<<<dim3(1), dim3(64), 0, stream>>>(d_in[0], flag);
  ConvJobs jobs;
  for (int i = 0; i < 18; ++i) { jobs.j[i].src = d_in[i]; jobs.j[i].dst = cin[i]; jobs.j[i].n = in_sizes[i]; }
  ingest_kernel<<<dim3(64, 18), blk, 0, stream>>>(jobs, flag);

  const float *x = cin[0], *memory = cin[1], *W_qvk = cin[2], *b_qvk = cin[3],
              *W_kv = cin[4], *b_kv = cin[5], *W_q = cin[6], *b_q = cin[7],
              *W_ff1 = cin[8], *b_ff1 = cin[9], *W_ff2 = cin[10], *b_ff2 = cin[11],
              *ln1_g = cin[12], *ln1_b = cin[13], *ln2_g = cin[14], *ln2_b = cin[15],
              *ln3_g = cin[16], *ln3_b = cin[17];

  // 1. qvk = x @ W_qvk + b
  gemm_kernel<false, false><<<dim3(3 * DIMc / 64, MR / 64), blk, 0, stream>>>(
      x, W_qvk, b_qvk, nullptr, qvk, MR, 3 * DIMc, DIMc);
  // 2. causal linear self-attention
  causalA<<<dim3(NCc, Bc * Hc), blk, 0, stream>>>(qvk, chunkKV, chunkKs);
  causalB<<<dim3(Bc * Hc), blk, 0, stream>>>(chunkKV, chunkKs);
  causalC<<<dim3(NCc, Bc * Hc), blk, 0, stream>>>(qvk, chunkKV, chunkKs, attn_o);
  // 3. LN1(attn + x)
  ln_kernel<true, false><<<dim3(MR), blk, 0, stream>>>(
      attn_o, x, ln1_g, ln1_b, out1, flag);
  // 4. kv = memory @ W_kv + b (overwrites dead qvk) ; q2 = out1 @ W_q + b
  gemm_kernel<false, false><<<dim3(2 * DIMc / 64, MR / 64), blk, 0, stream>>>(
      memory, W_kv, b_kv, nullptr, kvbuf, Bc * Mc, 2 * DIMc, DIMc);
  gemm_kernel<false, false><<<dim3(DIMc / 64, MR / 64), blk, 0, stream>>>(
      out1, W_q, b_q, nullptr, q2, MR, DIMc, DIMc);
  // 5. cross linear attention
  colsum_kernel<<<dim3(Bc * Hc), blk, 0, stream>>>(kvbuf, colsum);
  hipMemsetAsync(ctx2, 0, (size_t)Bc * Hc * Ec * Ec * sizeof(float), stream);
  ctx_kernel<<<dim3(Mc / 64, Bc * Hc), blk, 0, stream>>>(kvbuf, colsum, ctx2);
  attn2_kernel<<<dim3(Nc / 4, Bc * Hc), blk, 0, stream>>>(q2, ctx2, attn2_o);
  // 6. LN2(attn2 + out1) in-place
  ln_kernel<true, false><<<dim3(MR), blk, 0, stream>>>(
      attn2_o, out1, ln2_g, ln2_b, ybuf, flag);
  // 7. FF (ff1buf overwrites dead kvbuf/q2)
  gemm_kernel<true, false><<<dim3(FFc / 64, MR / 64), blk, 0, stream>>>(
      ybuf, W_ff1, b_ff1, nullptr, ff1buf, MR, FFc, DIMc);
  gemm_kernel<false, true><<<dim3(DIMc / 64, MR / 64), blk, 0, stream>>>(
      ff1buf, W_ff2, b_ff2, ybuf, pre3, MR, DIMc, FFc);
  // 8. LN3 -> d_out (bf16 or fp32 per flag)
  ln_kernel<false, true><<<dim3(MR), blk, 0, stream>>>(
      pre3, nullptr, ln3_g, ln3_b, d_out, flag);
}